// Round 1
// baseline (973.113 us; speedup 1.0000x reference)
//
#include <hip/hip_runtime.h>
#include <cstdint>
#include <cstddef>

#define NN 50000
#define EE 800000
#define ETOT 850000   // EE + NN self loops
#define NEG_SLOPE 0.2f

// ---------------- CSR build ----------------

__global__ __launch_bounds__(256) void deg_kernel(const int* __restrict__ ei, int* __restrict__ deg) {
    int e = blockIdx.x * 256 + threadIdx.x;
    if (e >= ETOT) return;
    int d = (e < EE) ? ei[EE + e] : (e - EE);
    atomicAdd(&deg[d], 1);
}

__global__ __launch_bounds__(256) void scan1_kernel(const int* __restrict__ deg, int* __restrict__ offs,
                                                    int* __restrict__ bsum, int n) {
    __shared__ int sh[256];
    int i = blockIdx.x * 256 + threadIdx.x;
    int v = (i < n) ? deg[i] : 0;
    sh[threadIdx.x] = v;
    __syncthreads();
    for (int off = 1; off < 256; off <<= 1) {
        int t = (threadIdx.x >= off) ? sh[threadIdx.x - off] : 0;
        __syncthreads();
        sh[threadIdx.x] += t;
        __syncthreads();
    }
    if (i < n) offs[i] = sh[threadIdx.x] - v;   // exclusive within block
    if (threadIdx.x == 255) bsum[blockIdx.x] = sh[255];
}

__global__ __launch_bounds__(256) void scan2_kernel(int* __restrict__ bsum, int nb) {
    __shared__ int sh[256];
    int v = (threadIdx.x < nb) ? bsum[threadIdx.x] : 0;
    sh[threadIdx.x] = v;
    __syncthreads();
    for (int off = 1; off < 256; off <<= 1) {
        int t = (threadIdx.x >= off) ? sh[threadIdx.x - off] : 0;
        __syncthreads();
        sh[threadIdx.x] += t;
        __syncthreads();
    }
    if (threadIdx.x < nb) bsum[threadIdx.x] = sh[threadIdx.x] - v;  // exclusive
}

__global__ __launch_bounds__(256) void scan3_kernel(const int* __restrict__ bsum, int* __restrict__ offs,
                                                    int* __restrict__ cursor, int n) {
    int i = blockIdx.x * 256 + threadIdx.x;
    if (i < n) {
        int o = offs[i] + bsum[blockIdx.x];
        offs[i] = o;
        cursor[i] = o;
    }
}

__global__ __launch_bounds__(256) void fill_kernel(const int* __restrict__ ei, int* __restrict__ cursor,
                                                   int* __restrict__ csrc, int* __restrict__ ceid) {
    int e = blockIdx.x * 256 + threadIdx.x;
    if (e >= ETOT) return;
    int d, s;
    if (e < EE) { s = ei[e]; d = ei[EE + e]; } else { s = e - EE; d = e - EE; }
    int p = atomicAdd(&cursor[d], 1);
    csrc[p] = s;
    ceid[p] = e;
}

// ---------------- GEMM (fp32, row-major A[MxK] * B[KxN] -> C[MxN]) ----------------
// N, K multiples of 64/16; M ragged.

__global__ __launch_bounds__(256) void gemm_kernel(const float* __restrict__ A, const float* __restrict__ B,
                                                   float* __restrict__ C, int M, int N, int K) {
    __shared__ float As[64][20];   // [row][k] pad to 20 (16B-aligned rows)
    __shared__ float Bs[16][64];   // [k][col]
    int t = threadIdx.x;
    int tx = t & 15, ty = t >> 4;
    int m0 = blockIdx.y * 64;
    int n0 = blockIdx.x * 64;
    int arow = t >> 2;            // 0..63
    int acol = (t & 3) * 4;       // 0,4,8,12
    int brow = t >> 4;            // 0..15
    int bcol = (t & 15) * 4;
    float acc[4][4] = {};
    for (int k0 = 0; k0 < K; k0 += 16) {
        float4 av = make_float4(0.f, 0.f, 0.f, 0.f);
        int gr = m0 + arow;
        if (gr < M) av = *(const float4*)(A + (size_t)gr * K + k0 + acol);
        *(float4*)(&As[arow][acol]) = av;
        float4 bv = *(const float4*)(B + (size_t)(k0 + brow) * N + n0 + bcol);
        *(float4*)(&Bs[brow][bcol]) = bv;
        __syncthreads();
#pragma unroll
        for (int k = 0; k < 16; ++k) {
            float a0 = As[ty * 4 + 0][k];
            float a1 = As[ty * 4 + 1][k];
            float a2 = As[ty * 4 + 2][k];
            float a3 = As[ty * 4 + 3][k];
            float4 b4 = *(const float4*)(&Bs[k][tx * 4]);
            acc[0][0] += a0 * b4.x; acc[0][1] += a0 * b4.y; acc[0][2] += a0 * b4.z; acc[0][3] += a0 * b4.w;
            acc[1][0] += a1 * b4.x; acc[1][1] += a1 * b4.y; acc[1][2] += a1 * b4.z; acc[1][3] += a1 * b4.w;
            acc[2][0] += a2 * b4.x; acc[2][1] += a2 * b4.y; acc[2][2] += a2 * b4.z; acc[2][3] += a2 * b4.w;
            acc[3][0] += a3 * b4.x; acc[3][1] += a3 * b4.y; acc[3][2] += a3 * b4.z; acc[3][3] += a3 * b4.w;
        }
        __syncthreads();
    }
#pragma unroll
    for (int i = 0; i < 4; ++i) {
        int gr = m0 + ty * 4 + i;
        if (gr < M) {
            float4 v = make_float4(acc[i][0], acc[i][1], acc[i][2], acc[i][3]);
            *(float4*)(C + (size_t)gr * N + n0 + tx * 4) = v;
        }
    }
}

// ---------------- attention score dots ----------------
// H [N,256] viewed [N,4,64]; a flat [256]. es[n,h] = sum_c H[n,h*64+c]*aS[h*64+c]

__global__ __launch_bounds__(256) void scores4_kernel(const float* __restrict__ H, const float* __restrict__ aS,
                                                      const float* __restrict__ aD, float* __restrict__ es,
                                                      float* __restrict__ ed) {
    int wave = threadIdx.x >> 6, lane = threadIdx.x & 63;
    int n = blockIdx.x * 4 + wave;
    if (n >= NN) return;
    float4 h = *(const float4*)(H + (size_t)n * 256 + lane * 4);
    float4 s4 = *(const float4*)(aS + lane * 4);
    float4 d4 = *(const float4*)(aD + lane * 4);
    float ps = h.x * s4.x + h.y * s4.y + h.z * s4.z + h.w * s4.w;
    float pd = h.x * d4.x + h.y * d4.y + h.z * d4.z + h.w * d4.w;
    for (int off = 1; off < 16; off <<= 1) { ps += __shfl_xor(ps, off); pd += __shfl_xor(pd, off); }
    if ((lane & 15) == 0) {
        int hh = lane >> 4;
        es[n * 4 + hh] = ps;
        ed[n * 4 + hh] = pd;
    }
}

// H [N,64] = [Hm | Hs]; a flat [64] = [am | as]. 2 pseudo-heads of 32 ch.
__global__ __launch_bounds__(256) void scores_ms_kernel(const float* __restrict__ H, const float* __restrict__ aS,
                                                        const float* __restrict__ aD, float* __restrict__ es,
                                                        float* __restrict__ ed) {
    int wave = threadIdx.x >> 6, lane = threadIdx.x & 63;
    int n = blockIdx.x * 4 + wave;
    if (n >= NN) return;
    float h = H[(size_t)n * 64 + lane];
    float ps = h * aS[lane];
    float pd = h * aD[lane];
    for (int off = 1; off < 32; off <<= 1) { ps += __shfl_xor(ps, off); pd += __shfl_xor(pd, off); }
    if ((lane & 31) == 0) {
        int g = lane >> 5;
        es[n * 2 + g] = ps;
        ed[n * 2 + g] = pd;
    }
}

__device__ __forceinline__ float leaky(float v) { return v > 0.f ? v : NEG_SLOPE * v; }

// ---------------- layer-1 aggregation (concat heads, +bias, relu) ----------------
__global__ __launch_bounds__(256) void agg_concat_kernel(
    const float* __restrict__ H, const float* __restrict__ es, const float* __restrict__ ed,
    const int* __restrict__ offs, const int* __restrict__ csrc, const int* __restrict__ ceid,
    const float* __restrict__ bias, float* __restrict__ out, float* __restrict__ alpha_out) {
    int wave = threadIdx.x >> 6, lane = threadIdx.x & 63;
    int n = blockIdx.x * 4 + wave;
    if (n >= NN) return;
    int h = lane >> 4, sub = lane & 15;
    int start = offs[n];
    int end = (n + 1 < NN) ? offs[n + 1] : ETOT;
    int deg = end - start;
    float edh = ed[n * 4 + h];
    float m = -INFINITY;
    for (int j = sub; j < deg; j += 16) {
        int s = csrc[start + j];
        m = fmaxf(m, leaky(es[s * 4 + h] + edh));
    }
    for (int off = 1; off < 16; off <<= 1) m = fmaxf(m, __shfl_xor(m, off));
    float dsum = 0.f;
    for (int j = sub; j < deg; j += 16) {
        int s = csrc[start + j];
        dsum += __expf(leaky(es[s * 4 + h] + edh) - m);
    }
    for (int off = 1; off < 16; off <<= 1) dsum += __shfl_xor(dsum, off);
    float inv = 1.f / (dsum + 1e-16f);
    float4 acc = make_float4(0.f, 0.f, 0.f, 0.f);
    int cbase = lane * 4;
    for (int j = 0; j < deg; ++j) {
        int s = csrc[start + j];
        float a = __expf(leaky(es[s * 4 + h] + edh) - m) * inv;
        if (sub == 0) alpha_out[(size_t)ceid[start + j] * 4 + h] = a;
        float4 v = *(const float4*)(H + (size_t)s * 256 + cbase);
        acc.x += a * v.x; acc.y += a * v.y; acc.z += a * v.z; acc.w += a * v.w;
    }
    float4 b = *(const float4*)(bias + cbase);
    acc.x = fmaxf(acc.x + b.x, 0.f);
    acc.y = fmaxf(acc.y + b.y, 0.f);
    acc.z = fmaxf(acc.z + b.z, 0.f);
    acc.w = fmaxf(acc.w + b.w, 0.f);
    *(float4*)(out + (size_t)n * 256 + cbase) = acc;
}

// ---------------- layer-2 aggregation (mean over 4 heads, +bias, relu) ----------------
__global__ __launch_bounds__(256) void agg_mean_kernel(
    const float* __restrict__ H, const float* __restrict__ es, const float* __restrict__ ed,
    const int* __restrict__ offs, const int* __restrict__ csrc, const int* __restrict__ ceid,
    const float* __restrict__ bias, float* __restrict__ out, float* __restrict__ alpha_out) {
    int wave = threadIdx.x >> 6, lane = threadIdx.x & 63;
    int n = blockIdx.x * 4 + wave;
    if (n >= NN) return;
    int h = lane >> 4, sub = lane & 15;
    int start = offs[n];
    int end = (n + 1 < NN) ? offs[n + 1] : ETOT;
    int deg = end - start;
    float edh = ed[n * 4 + h];
    float m = -INFINITY;
    for (int j = sub; j < deg; j += 16) {
        int s = csrc[start + j];
        m = fmaxf(m, leaky(es[s * 4 + h] + edh));
    }
    for (int off = 1; off < 16; off <<= 1) m = fmaxf(m, __shfl_xor(m, off));
    float dsum = 0.f;
    for (int j = sub; j < deg; j += 16) {
        int s = csrc[start + j];
        dsum += __expf(leaky(es[s * 4 + h] + edh) - m);
    }
    for (int off = 1; off < 16; off <<= 1) dsum += __shfl_xor(dsum, off);
    float inv = 1.f / (dsum + 1e-16f);
    float4 acc = make_float4(0.f, 0.f, 0.f, 0.f);
    int cbase = lane * 4;
    for (int j = 0; j < deg; ++j) {
        int s = csrc[start + j];
        float a = __expf(leaky(es[s * 4 + h] + edh) - m) * inv;
        if (sub == 0) alpha_out[(size_t)ceid[start + j] * 4 + h] = a;
        float4 v = *(const float4*)(H + (size_t)s * 256 + cbase);
        acc.x += a * v.x; acc.y += a * v.y; acc.z += a * v.z; acc.w += a * v.w;
    }
    // sum across the 4 heads (lanes l, l^16, l^32, l^48 hold same channel)
    acc.x += __shfl_xor(acc.x, 16); acc.y += __shfl_xor(acc.y, 16);
    acc.z += __shfl_xor(acc.z, 16); acc.w += __shfl_xor(acc.w, 16);
    acc.x += __shfl_xor(acc.x, 32); acc.y += __shfl_xor(acc.y, 32);
    acc.z += __shfl_xor(acc.z, 32); acc.w += __shfl_xor(acc.w, 32);
    if (lane < 16) {
        float4 b = *(const float4*)(bias + lane * 4);
        float4 r;
        r.x = fmaxf(acc.x * 0.25f + b.x, 0.f);
        r.y = fmaxf(acc.y * 0.25f + b.y, 0.f);
        r.z = fmaxf(acc.z * 0.25f + b.z, 0.f);
        r.w = fmaxf(acc.w * 0.25f + b.w, 0.f);
        *(float4*)(out + (size_t)n * 64 + lane * 4) = r;
    }
}

// ---------------- mean/log_std heads aggregation (2 pseudo-heads of 32 ch) ----------------
__global__ __launch_bounds__(256) void agg_ms_kernel(
    const float* __restrict__ H, const float* __restrict__ es, const float* __restrict__ ed,
    const int* __restrict__ offs, const int* __restrict__ csrc, const int* __restrict__ ceid,
    const float* __restrict__ bm, const float* __restrict__ bs,
    float* __restrict__ zmean, float* __restrict__ zlog,
    float* __restrict__ a_wm, float* __restrict__ a_ws) {
    int wave = threadIdx.x >> 6, lane = threadIdx.x & 63;
    int n = blockIdx.x * 4 + wave;
    if (n >= NN) return;
    int g = lane >> 5, sub = lane & 31;
    int start = offs[n];
    int end = (n + 1 < NN) ? offs[n + 1] : ETOT;
    int deg = end - start;
    float edh = ed[n * 2 + g];
    float m = -INFINITY;
    for (int j = sub; j < deg; j += 32) {
        int s = csrc[start + j];
        m = fmaxf(m, leaky(es[s * 2 + g] + edh));
    }
    for (int off = 1; off < 32; off <<= 1) m = fmaxf(m, __shfl_xor(m, off));
    float dsum = 0.f;
    for (int j = sub; j < deg; j += 32) {
        int s = csrc[start + j];
        dsum += __expf(leaky(es[s * 2 + g] + edh) - m);
    }
    for (int off = 1; off < 32; off <<= 1) dsum += __shfl_xor(dsum, off);
    float inv = 1.f / (dsum + 1e-16f);
    float acc = 0.f;
    for (int j = 0; j < deg; ++j) {
        int s = csrc[start + j];
        float a = __expf(leaky(es[s * 2 + g] + edh) - m) * inv;
        if (sub == 0) {
            int eid = ceid[start + j];
            if (g == 0) a_wm[eid] = a; else a_ws[eid] = a;
        }
        acc += a * H[(size_t)s * 64 + lane];
    }
    if (g == 0) zmean[(size_t)n * 32 + sub] = acc + bm[sub];
    else        zlog[(size_t)n * 32 + sub] = acc + bs[sub];
}

// ---------------- pack combined mean/log_std weights ----------------
__global__ __launch_bounds__(256) void pack_ms_kernel(const float* __restrict__ Wm, const float* __restrict__ Ws,
                                                      const float* __restrict__ ams, const float* __restrict__ ass,
                                                      const float* __restrict__ amd, const float* __restrict__ asd,
                                                      float* __restrict__ Wms, float* __restrict__ aS,
                                                      float* __restrict__ aD) {
    int i = blockIdx.x * 256 + threadIdx.x;
    if (i < 4096) {
        int k = i >> 6, c = i & 63;
        Wms[i] = (c < 32) ? Wm[k * 32 + c] : Ws[k * 32 + (c - 32)];
    }
    if (i < 64) {
        aS[i] = (i < 32) ? ams[i] : ass[i - 32];
        aD[i] = (i < 32) ? amd[i] : asd[i - 32];
    }
}

// ---------------- launch ----------------

extern "C" void kernel_launch(void* const* d_in, const int* in_sizes, int n_in,
                              void* d_out, int out_size, void* d_ws, size_t ws_size,
                              hipStream_t stream) {
    const float* x   = (const float*)d_in[0];
    const int*   ei  = (const int*)d_in[1];
    const float* W1  = (const float*)d_in[2];
    const float* a1s = (const float*)d_in[3];
    const float* a1d = (const float*)d_in[4];
    const float* b1  = (const float*)d_in[5];
    const float* W2  = (const float*)d_in[6];
    const float* a2s = (const float*)d_in[7];
    const float* a2d = (const float*)d_in[8];
    const float* b2  = (const float*)d_in[9];
    const float* Wm  = (const float*)d_in[10];
    const float* ams = (const float*)d_in[11];
    const float* amd = (const float*)d_in[12];
    const float* bm  = (const float*)d_in[13];
    const float* Ws  = (const float*)d_in[14];
    const float* ass = (const float*)d_in[15];
    const float* asd = (const float*)d_in[16];
    const float* bs  = (const float*)d_in[17];

    float* out = (float*)d_out;
    float* zmean = out;                       // [50000,32]
    float* zlog  = out + 1600000;             // [50000,32]
    float* a_w1  = out + 3200000;             // [850000,4]
    float* a_w2  = out + 6600000;             // [850000,4]
    float* a_wm  = out + 10000000;            // [850000]
    float* a_ws_o = out + 10850000;           // [850000]

    float* ws = (float*)d_ws;
    size_t o = 0;
    float* bufA = ws + o; o += (size_t)NN * 256;   // H1 then H2
    float* bufB = ws + o; o += (size_t)NN * 256;   // h1relu then Hms
    float* h2   = ws + o; o += (size_t)NN * 64;
    float* es1  = ws + o; o += NN * 4;
    float* ed1  = ws + o; o += NN * 4;
    float* es2  = ws + o; o += NN * 4;
    float* ed2  = ws + o; o += NN * 4;
    float* esms = ws + o; o += NN * 2;
    float* edms = ws + o; o += NN * 2;
    float* Wms  = ws + o; o += 4096;
    float* aSms = ws + o; o += 64;
    float* aDms = ws + o; o += 64;
    int* deg    = (int*)(ws + o); o += NN;
    int* offs   = (int*)(ws + o); o += NN;
    int* cursor = (int*)(ws + o); o += NN;
    int* csrc   = (int*)(ws + o); o += ETOT;
    int* ceid   = (int*)(ws + o); o += ETOT;

    const int edgeBlocks = (ETOT + 255) / 256;   // 3321
    const int nodeBlocks = (NN + 255) / 256;     // 196
    const int waveBlocks = (NN + 3) / 4;         // 12500

    // ---- CSR build ----
    hipMemsetAsync(deg, 0, NN * sizeof(int), stream);
    deg_kernel<<<edgeBlocks, 256, 0, stream>>>(ei, deg);
    scan1_kernel<<<nodeBlocks, 256, 0, stream>>>(deg, offs, cursor /*tmp bsum*/, NN);
    scan2_kernel<<<1, 256, 0, stream>>>(cursor, nodeBlocks);
    scan3_kernel<<<nodeBlocks, 256, 0, stream>>>(cursor, offs, deg /*reuse as cursor*/, NN);
    // after scan3: offs = final offsets, deg[] = working cursor
    fill_kernel<<<edgeBlocks, 256, 0, stream>>>(ei, deg, csrc, ceid);

    // ---- pack mean/log_std weights ----
    pack_ms_kernel<<<16, 256, 0, stream>>>(Wm, Ws, ams, ass, amd, asd, Wms, aSms, aDms);

    dim3 g1(4, (NN + 63) / 64);
    // ---- layer 1 ----
    gemm_kernel<<<g1, 256, 0, stream>>>(x, W1, bufA, NN, 256, 256);
    scores4_kernel<<<waveBlocks, 256, 0, stream>>>(bufA, a1s, a1d, es1, ed1);
    agg_concat_kernel<<<waveBlocks, 256, 0, stream>>>(bufA, es1, ed1, offs, csrc, ceid, b1, bufB, a_w1);

    // ---- layer 2 ----
    gemm_kernel<<<g1, 256, 0, stream>>>(bufB, W2, bufA, NN, 256, 256);
    scores4_kernel<<<waveBlocks, 256, 0, stream>>>(bufA, a2s, a2d, es2, ed2);
    agg_mean_kernel<<<waveBlocks, 256, 0, stream>>>(bufA, es2, ed2, offs, csrc, ceid, b2, h2, a_w2);

    // ---- mean / log_std heads ----
    dim3 g2(1, (NN + 63) / 64);
    gemm_kernel<<<g2, 256, 0, stream>>>(h2, Wms, bufB, NN, 64, 64);
    scores_ms_kernel<<<waveBlocks, 256, 0, stream>>>(bufB, aSms, aDms, esms, edms);
    agg_ms_kernel<<<waveBlocks, 256, 0, stream>>>(bufB, esms, edms, offs, csrc, ceid, bm, bs,
                                                  zmean, zlog, a_wm, a_ws_o);
}

// Round 2
// 795.837 us; speedup vs baseline: 1.2228x; 1.2228x over previous
//
#include <hip/hip_runtime.h>
#include <cstdint>
#include <cstddef>

#define NN 50000
#define EE 800000
#define ETOT 850000   // EE + NN self loops
#define NEG_SLOPE 0.2f

// ---------------- CSR build ----------------

__global__ __launch_bounds__(256) void deg_kernel(const int* __restrict__ ei, int* __restrict__ deg) {
    int e = blockIdx.x * 256 + threadIdx.x;
    if (e >= ETOT) return;
    int d = (e < EE) ? ei[EE + e] : (e - EE);
    atomicAdd(&deg[d], 1);
}

__global__ __launch_bounds__(256) void scan1_kernel(const int* __restrict__ deg, int* __restrict__ offs,
                                                    int* __restrict__ bsum, int n) {
    __shared__ int sh[256];
    int i = blockIdx.x * 256 + threadIdx.x;
    int v = (i < n) ? deg[i] : 0;
    sh[threadIdx.x] = v;
    __syncthreads();
    for (int off = 1; off < 256; off <<= 1) {
        int t = (threadIdx.x >= off) ? sh[threadIdx.x - off] : 0;
        __syncthreads();
        sh[threadIdx.x] += t;
        __syncthreads();
    }
    if (i < n) offs[i] = sh[threadIdx.x] - v;   // exclusive within block
    if (threadIdx.x == 255) bsum[blockIdx.x] = sh[255];
}

__global__ __launch_bounds__(256) void scan2_kernel(int* __restrict__ bsum, int nb) {
    __shared__ int sh[256];
    int v = (threadIdx.x < nb) ? bsum[threadIdx.x] : 0;
    sh[threadIdx.x] = v;
    __syncthreads();
    for (int off = 1; off < 256; off <<= 1) {
        int t = (threadIdx.x >= off) ? sh[threadIdx.x - off] : 0;
        __syncthreads();
        sh[threadIdx.x] += t;
        __syncthreads();
    }
    if (threadIdx.x < nb) bsum[threadIdx.x] = sh[threadIdx.x] - v;  // exclusive
}

__global__ __launch_bounds__(256) void scan3_kernel(const int* __restrict__ bsum, int* __restrict__ offs,
                                                    int* __restrict__ cursor, int n) {
    int i = blockIdx.x * 256 + threadIdx.x;
    if (i < n) {
        int o = offs[i] + bsum[blockIdx.x];
        offs[i] = o;
        cursor[i] = o;
    }
}

__global__ __launch_bounds__(256) void fill_kernel(const int* __restrict__ ei, int* __restrict__ cursor,
                                                   int* __restrict__ csrc, int* __restrict__ ceid) {
    int e = blockIdx.x * 256 + threadIdx.x;
    if (e >= ETOT) return;
    int d, s;
    if (e < EE) { s = ei[e]; d = ei[EE + e]; } else { s = e - EE; d = e - EE; }
    int p = atomicAdd(&cursor[d], 1);
    csrc[p] = s;
    ceid[p] = e;
}

// ---------------- GEMM (fp32, row-major A[MxK] * B[KxN] -> C[MxN]) ----------------

__global__ __launch_bounds__(256) void gemm_kernel(const float* __restrict__ A, const float* __restrict__ B,
                                                   float* __restrict__ C, int M, int N, int K) {
    __shared__ float As[64][20];
    __shared__ float Bs[16][64];
    int t = threadIdx.x;
    int tx = t & 15, ty = t >> 4;
    int m0 = blockIdx.y * 64;
    int n0 = blockIdx.x * 64;
    int arow = t >> 2;
    int acol = (t & 3) * 4;
    int brow = t >> 4;
    int bcol = (t & 15) * 4;
    float acc[4][4] = {};
    for (int k0 = 0; k0 < K; k0 += 16) {
        float4 av = make_float4(0.f, 0.f, 0.f, 0.f);
        int gr = m0 + arow;
        if (gr < M) av = *(const float4*)(A + (size_t)gr * K + k0 + acol);
        *(float4*)(&As[arow][acol]) = av;
        float4 bv = *(const float4*)(B + (size_t)(k0 + brow) * N + n0 + bcol);
        *(float4*)(&Bs[brow][bcol]) = bv;
        __syncthreads();
#pragma unroll
        for (int k = 0; k < 16; ++k) {
            float a0 = As[ty * 4 + 0][k];
            float a1 = As[ty * 4 + 1][k];
            float a2 = As[ty * 4 + 2][k];
            float a3 = As[ty * 4 + 3][k];
            float4 b4 = *(const float4*)(&Bs[k][tx * 4]);
            acc[0][0] += a0 * b4.x; acc[0][1] += a0 * b4.y; acc[0][2] += a0 * b4.z; acc[0][3] += a0 * b4.w;
            acc[1][0] += a1 * b4.x; acc[1][1] += a1 * b4.y; acc[1][2] += a1 * b4.z; acc[1][3] += a1 * b4.w;
            acc[2][0] += a2 * b4.x; acc[2][1] += a2 * b4.y; acc[2][2] += a2 * b4.z; acc[2][3] += a2 * b4.w;
            acc[3][0] += a3 * b4.x; acc[3][1] += a3 * b4.y; acc[3][2] += a3 * b4.z; acc[3][3] += a3 * b4.w;
        }
        __syncthreads();
    }
#pragma unroll
    for (int i = 0; i < 4; ++i) {
        int gr = m0 + ty * 4 + i;
        if (gr < M) {
            float4 v = make_float4(acc[i][0], acc[i][1], acc[i][2], acc[i][3]);
            *(float4*)(C + (size_t)gr * N + n0 + tx * 4) = v;
        }
    }
}

// ---------------- attention score dots ----------------

__global__ __launch_bounds__(256) void scores4_kernel(const float* __restrict__ H, const float* __restrict__ aS,
                                                      const float* __restrict__ aD, float* __restrict__ es,
                                                      float* __restrict__ ed) {
    int wave = threadIdx.x >> 6, lane = threadIdx.x & 63;
    int n = blockIdx.x * 4 + wave;
    if (n >= NN) return;
    float4 h = *(const float4*)(H + (size_t)n * 256 + lane * 4);
    float4 s4 = *(const float4*)(aS + lane * 4);
    float4 d4 = *(const float4*)(aD + lane * 4);
    float ps = h.x * s4.x + h.y * s4.y + h.z * s4.z + h.w * s4.w;
    float pd = h.x * d4.x + h.y * d4.y + h.z * d4.z + h.w * d4.w;
    for (int off = 1; off < 16; off <<= 1) { ps += __shfl_xor(ps, off); pd += __shfl_xor(pd, off); }
    if ((lane & 15) == 0) {
        int hh = lane >> 4;
        es[n * 4 + hh] = ps;
        ed[n * 4 + hh] = pd;
    }
}

__global__ __launch_bounds__(256) void scores_ms_kernel(const float* __restrict__ H, const float* __restrict__ aS,
                                                        const float* __restrict__ aD, float* __restrict__ es,
                                                        float* __restrict__ ed) {
    int wave = threadIdx.x >> 6, lane = threadIdx.x & 63;
    int n = blockIdx.x * 4 + wave;
    if (n >= NN) return;
    float h = H[(size_t)n * 64 + lane];
    float ps = h * aS[lane];
    float pd = h * aD[lane];
    for (int off = 1; off < 32; off <<= 1) { ps += __shfl_xor(ps, off); pd += __shfl_xor(pd, off); }
    if ((lane & 31) == 0) {
        int g = lane >> 5;
        es[n * 2 + g] = ps;
        ed[n * 2 + g] = pd;
    }
}

__device__ __forceinline__ float leaky(float v) { return v > 0.f ? v : NEG_SLOPE * v; }

// ---------------- softmax alpha (CSR order) for the 4-head layers ----------------
// Writes alpha into etmp[(csr_pos)*4+h] AND alpha_out[eid*4+h]. All passes lane-parallel.

__device__ __forceinline__ void softmax4(
    int n, int lane, const float* __restrict__ es, const float* __restrict__ ed,
    const int* __restrict__ offs, const int* __restrict__ csrc, const int* __restrict__ ceid,
    float* __restrict__ etmp, float* __restrict__ alpha_out, int start, int deg) {
    int h = lane >> 4, sub = lane & 15;
    float edh = ed[n * 4 + h];
    float m = -INFINITY;
    for (int j = sub; j < deg; j += 16) {
        int s = csrc[start + j];
        float v = leaky(es[s * 4 + h] + edh);
        etmp[(size_t)(start + j) * 4 + h] = v;
        m = fmaxf(m, v);
    }
    for (int off = 1; off < 16; off <<= 1) m = fmaxf(m, __shfl_xor(m, off));
    float dsum = 0.f;
    for (int j = sub; j < deg; j += 16) {
        float t = __expf(etmp[(size_t)(start + j) * 4 + h] - m);
        etmp[(size_t)(start + j) * 4 + h] = t;
        dsum += t;
    }
    for (int off = 1; off < 16; off <<= 1) dsum += __shfl_xor(dsum, off);
    float inv = 1.f / (dsum + 1e-16f);
    for (int j = sub; j < deg; j += 16) {
        float a = etmp[(size_t)(start + j) * 4 + h] * inv;
        etmp[(size_t)(start + j) * 4 + h] = a;
        alpha_out[(size_t)ceid[start + j] * 4 + h] = a;
    }
}

// ---------------- layer-1 aggregation (concat heads, +bias, relu) ----------------
__global__ __launch_bounds__(256) void agg_concat_kernel(
    const float* __restrict__ H, const float* __restrict__ es, const float* __restrict__ ed,
    const int* __restrict__ offs, const int* __restrict__ csrc, const int* __restrict__ ceid,
    const float* __restrict__ bias, float* __restrict__ out, float* __restrict__ alpha_out,
    float* __restrict__ etmp) {
    int wave = threadIdx.x >> 6, lane = threadIdx.x & 63;
    int n = blockIdx.x * 4 + wave;
    if (n >= NN) return;
    int h = lane >> 4;
    int start = offs[n];
    int end = (n + 1 < NN) ? offs[n + 1] : ETOT;
    int deg = end - start;
    softmax4(n, lane, es, ed, offs, csrc, ceid, etmp, alpha_out, start, deg);
    int cbase = lane * 4;
    float4 acc0 = {}, acc1 = {}, acc2 = {}, acc3 = {};
    int j = 0;
    for (; j + 3 < deg; j += 4) {
        int p = start + j;
        int s0 = csrc[p], s1 = csrc[p + 1], s2 = csrc[p + 2], s3 = csrc[p + 3];
        float a0 = etmp[(size_t)p * 4 + h];
        float a1 = etmp[(size_t)(p + 1) * 4 + h];
        float a2 = etmp[(size_t)(p + 2) * 4 + h];
        float a3 = etmp[(size_t)(p + 3) * 4 + h];
        float4 v0 = *(const float4*)(H + (size_t)s0 * 256 + cbase);
        float4 v1 = *(const float4*)(H + (size_t)s1 * 256 + cbase);
        float4 v2 = *(const float4*)(H + (size_t)s2 * 256 + cbase);
        float4 v3 = *(const float4*)(H + (size_t)s3 * 256 + cbase);
        acc0.x += a0 * v0.x; acc0.y += a0 * v0.y; acc0.z += a0 * v0.z; acc0.w += a0 * v0.w;
        acc1.x += a1 * v1.x; acc1.y += a1 * v1.y; acc1.z += a1 * v1.z; acc1.w += a1 * v1.w;
        acc2.x += a2 * v2.x; acc2.y += a2 * v2.y; acc2.z += a2 * v2.z; acc2.w += a2 * v2.w;
        acc3.x += a3 * v3.x; acc3.y += a3 * v3.y; acc3.z += a3 * v3.z; acc3.w += a3 * v3.w;
    }
    for (; j < deg; ++j) {
        int p = start + j;
        int s0 = csrc[p];
        float a0 = etmp[(size_t)p * 4 + h];
        float4 v0 = *(const float4*)(H + (size_t)s0 * 256 + cbase);
        acc0.x += a0 * v0.x; acc0.y += a0 * v0.y; acc0.z += a0 * v0.z; acc0.w += a0 * v0.w;
    }
    float4 acc;
    acc.x = (acc0.x + acc1.x) + (acc2.x + acc3.x);
    acc.y = (acc0.y + acc1.y) + (acc2.y + acc3.y);
    acc.z = (acc0.z + acc1.z) + (acc2.z + acc3.z);
    acc.w = (acc0.w + acc1.w) + (acc2.w + acc3.w);
    float4 b = *(const float4*)(bias + cbase);
    acc.x = fmaxf(acc.x + b.x, 0.f);
    acc.y = fmaxf(acc.y + b.y, 0.f);
    acc.z = fmaxf(acc.z + b.z, 0.f);
    acc.w = fmaxf(acc.w + b.w, 0.f);
    *(float4*)(out + (size_t)n * 256 + cbase) = acc;
}

// ---------------- layer-2 aggregation (mean over 4 heads, +bias, relu) ----------------
__global__ __launch_bounds__(256) void agg_mean_kernel(
    const float* __restrict__ H, const float* __restrict__ es, const float* __restrict__ ed,
    const int* __restrict__ offs, const int* __restrict__ csrc, const int* __restrict__ ceid,
    const float* __restrict__ bias, float* __restrict__ out, float* __restrict__ alpha_out,
    float* __restrict__ etmp) {
    int wave = threadIdx.x >> 6, lane = threadIdx.x & 63;
    int n = blockIdx.x * 4 + wave;
    if (n >= NN) return;
    int h = lane >> 4;
    int start = offs[n];
    int end = (n + 1 < NN) ? offs[n + 1] : ETOT;
    int deg = end - start;
    softmax4(n, lane, es, ed, offs, csrc, ceid, etmp, alpha_out, start, deg);
    int cbase = lane * 4;
    float4 acc0 = {}, acc1 = {}, acc2 = {}, acc3 = {};
    int j = 0;
    for (; j + 3 < deg; j += 4) {
        int p = start + j;
        int s0 = csrc[p], s1 = csrc[p + 1], s2 = csrc[p + 2], s3 = csrc[p + 3];
        float a0 = etmp[(size_t)p * 4 + h];
        float a1 = etmp[(size_t)(p + 1) * 4 + h];
        float a2 = etmp[(size_t)(p + 2) * 4 + h];
        float a3 = etmp[(size_t)(p + 3) * 4 + h];
        float4 v0 = *(const float4*)(H + (size_t)s0 * 256 + cbase);
        float4 v1 = *(const float4*)(H + (size_t)s1 * 256 + cbase);
        float4 v2 = *(const float4*)(H + (size_t)s2 * 256 + cbase);
        float4 v3 = *(const float4*)(H + (size_t)s3 * 256 + cbase);
        acc0.x += a0 * v0.x; acc0.y += a0 * v0.y; acc0.z += a0 * v0.z; acc0.w += a0 * v0.w;
        acc1.x += a1 * v1.x; acc1.y += a1 * v1.y; acc1.z += a1 * v1.z; acc1.w += a1 * v1.w;
        acc2.x += a2 * v2.x; acc2.y += a2 * v2.y; acc2.z += a2 * v2.z; acc2.w += a2 * v2.w;
        acc3.x += a3 * v3.x; acc3.y += a3 * v3.y; acc3.z += a3 * v3.z; acc3.w += a3 * v3.w;
    }
    for (; j < deg; ++j) {
        int p = start + j;
        int s0 = csrc[p];
        float a0 = etmp[(size_t)p * 4 + h];
        float4 v0 = *(const float4*)(H + (size_t)s0 * 256 + cbase);
        acc0.x += a0 * v0.x; acc0.y += a0 * v0.y; acc0.z += a0 * v0.z; acc0.w += a0 * v0.w;
    }
    float4 acc;
    acc.x = (acc0.x + acc1.x) + (acc2.x + acc3.x);
    acc.y = (acc0.y + acc1.y) + (acc2.y + acc3.y);
    acc.z = (acc0.z + acc1.z) + (acc2.z + acc3.z);
    acc.w = (acc0.w + acc1.w) + (acc2.w + acc3.w);
    // sum across the 4 heads (lanes l, l^16, l^32, l^48 hold same channel)
    acc.x += __shfl_xor(acc.x, 16); acc.y += __shfl_xor(acc.y, 16);
    acc.z += __shfl_xor(acc.z, 16); acc.w += __shfl_xor(acc.w, 16);
    acc.x += __shfl_xor(acc.x, 32); acc.y += __shfl_xor(acc.y, 32);
    acc.z += __shfl_xor(acc.z, 32); acc.w += __shfl_xor(acc.w, 32);
    if (lane < 16) {
        float4 b = *(const float4*)(bias + lane * 4);
        float4 r;
        r.x = fmaxf(acc.x * 0.25f + b.x, 0.f);
        r.y = fmaxf(acc.y * 0.25f + b.y, 0.f);
        r.z = fmaxf(acc.z * 0.25f + b.z, 0.f);
        r.w = fmaxf(acc.w * 0.25f + b.w, 0.f);
        *(float4*)(out + (size_t)n * 64 + lane * 4) = r;
    }
}

// ---------------- mean/log_std heads aggregation (2 pseudo-heads of 32 ch) ----------------
__global__ __launch_bounds__(256) void agg_ms_kernel(
    const float* __restrict__ H, const float* __restrict__ es, const float* __restrict__ ed,
    const int* __restrict__ offs, const int* __restrict__ csrc, const int* __restrict__ ceid,
    const float* __restrict__ bm, const float* __restrict__ bs,
    float* __restrict__ zmean, float* __restrict__ zlog,
    float* __restrict__ a_wm, float* __restrict__ a_ws,
    float* __restrict__ etmp) {
    int wave = threadIdx.x >> 6, lane = threadIdx.x & 63;
    int n = blockIdx.x * 4 + wave;
    if (n >= NN) return;
    int g = lane >> 5, sub = lane & 31;
    int start = offs[n];
    int end = (n + 1 < NN) ? offs[n + 1] : ETOT;
    int deg = end - start;
    float edh = ed[n * 2 + g];
    float m = -INFINITY;
    for (int j = sub; j < deg; j += 32) {
        int s = csrc[start + j];
        float v = leaky(es[s * 2 + g] + edh);
        etmp[(size_t)(start + j) * 2 + g] = v;
        m = fmaxf(m, v);
    }
    for (int off = 1; off < 32; off <<= 1) m = fmaxf(m, __shfl_xor(m, off));
    float dsum = 0.f;
    for (int j = sub; j < deg; j += 32) {
        float t = __expf(etmp[(size_t)(start + j) * 2 + g] - m);
        etmp[(size_t)(start + j) * 2 + g] = t;
        dsum += t;
    }
    for (int off = 1; off < 32; off <<= 1) dsum += __shfl_xor(dsum, off);
    float inv = 1.f / (dsum + 1e-16f);
    for (int j = sub; j < deg; j += 32) {
        float a = etmp[(size_t)(start + j) * 2 + g] * inv;
        etmp[(size_t)(start + j) * 2 + g] = a;
        int eid = ceid[start + j];
        if (g == 0) a_wm[eid] = a; else a_ws[eid] = a;
    }
    float acc0 = 0.f, acc1 = 0.f, acc2 = 0.f, acc3 = 0.f;
    int j = 0;
    for (; j + 3 < deg; j += 4) {
        int p = start + j;
        int s0 = csrc[p], s1 = csrc[p + 1], s2 = csrc[p + 2], s3 = csrc[p + 3];
        float a0 = etmp[(size_t)p * 2 + g];
        float a1 = etmp[(size_t)(p + 1) * 2 + g];
        float a2 = etmp[(size_t)(p + 2) * 2 + g];
        float a3 = etmp[(size_t)(p + 3) * 2 + g];
        acc0 += a0 * H[(size_t)s0 * 64 + lane];
        acc1 += a1 * H[(size_t)s1 * 64 + lane];
        acc2 += a2 * H[(size_t)s2 * 64 + lane];
        acc3 += a3 * H[(size_t)s3 * 64 + lane];
    }
    for (; j < deg; ++j) {
        int p = start + j;
        int s0 = csrc[p];
        float a0 = etmp[(size_t)p * 2 + g];
        acc0 += a0 * H[(size_t)s0 * 64 + lane];
    }
    float acc = (acc0 + acc1) + (acc2 + acc3);
    if (g == 0) zmean[(size_t)n * 32 + sub] = acc + bm[sub];
    else        zlog[(size_t)n * 32 + sub] = acc + bs[sub];
}

// ---------------- pack combined mean/log_std weights ----------------
__global__ __launch_bounds__(256) void pack_ms_kernel(const float* __restrict__ Wm, const float* __restrict__ Ws,
                                                      const float* __restrict__ ams, const float* __restrict__ ass,
                                                      const float* __restrict__ amd, const float* __restrict__ asd,
                                                      float* __restrict__ Wms, float* __restrict__ aS,
                                                      float* __restrict__ aD) {
    int i = blockIdx.x * 256 + threadIdx.x;
    if (i < 4096) {
        int k = i >> 6, c = i & 63;
        Wms[i] = (c < 32) ? Wm[k * 32 + c] : Ws[k * 32 + (c - 32)];
    }
    if (i < 64) {
        aS[i] = (i < 32) ? ams[i] : ass[i - 32];
        aD[i] = (i < 32) ? amd[i] : asd[i - 32];
    }
}

// ---------------- launch ----------------

extern "C" void kernel_launch(void* const* d_in, const int* in_sizes, int n_in,
                              void* d_out, int out_size, void* d_ws, size_t ws_size,
                              hipStream_t stream) {
    const float* x   = (const float*)d_in[0];
    const int*   ei  = (const int*)d_in[1];
    const float* W1  = (const float*)d_in[2];
    const float* a1s = (const float*)d_in[3];
    const float* a1d = (const float*)d_in[4];
    const float* b1  = (const float*)d_in[5];
    const float* W2  = (const float*)d_in[6];
    const float* a2s = (const float*)d_in[7];
    const float* a2d = (const float*)d_in[8];
    const float* b2  = (const float*)d_in[9];
    const float* Wm  = (const float*)d_in[10];
    const float* ams = (const float*)d_in[11];
    const float* amd = (const float*)d_in[12];
    const float* bm  = (const float*)d_in[13];
    const float* Ws  = (const float*)d_in[14];
    const float* ass = (const float*)d_in[15];
    const float* asd = (const float*)d_in[16];
    const float* bs  = (const float*)d_in[17];

    float* out = (float*)d_out;
    float* zmean = out;                       // [50000,32]
    float* zlog  = out + 1600000;             // [50000,32]
    float* a_w1  = out + 3200000;             // [850000,4]
    float* a_w2  = out + 6600000;             // [850000,4]
    float* a_wm  = out + 10000000;            // [850000]
    float* a_ws_o = out + 10850000;           // [850000]

    float* ws = (float*)d_ws;
    size_t o = 0;
    float* bufA = ws + o; o += (size_t)NN * 256;   // H1 then H2
    float* bufB = ws + o; o += (size_t)NN * 256;   // h1relu then Hms
    float* h2   = ws + o; o += (size_t)NN * 64;
    float* etmp = ws + o; o += (size_t)ETOT * 4;   // CSR-order scores/alpha scratch
    float* es1  = ws + o; o += NN * 4;
    float* ed1  = ws + o; o += NN * 4;
    float* es2  = ws + o; o += NN * 4;
    float* ed2  = ws + o; o += NN * 4;
    float* esms = ws + o; o += NN * 2;
    float* edms = ws + o; o += NN * 2;
    float* Wms  = ws + o; o += 4096;
    float* aSms = ws + o; o += 64;
    float* aDms = ws + o; o += 64;
    int* deg    = (int*)(ws + o); o += NN;
    int* offs   = (int*)(ws + o); o += NN;
    int* cursor = (int*)(ws + o); o += NN;
    int* csrc   = (int*)(ws + o); o += ETOT;
    int* ceid   = (int*)(ws + o); o += ETOT;

    const int edgeBlocks = (ETOT + 255) / 256;   // 3321
    const int nodeBlocks = (NN + 255) / 256;     // 196
    const int waveBlocks = (NN + 3) / 4;         // 12500

    // ---- CSR build ----
    hipMemsetAsync(deg, 0, NN * sizeof(int), stream);
    deg_kernel<<<edgeBlocks, 256, 0, stream>>>(ei, deg);
    scan1_kernel<<<nodeBlocks, 256, 0, stream>>>(deg, offs, cursor /*tmp bsum*/, NN);
    scan2_kernel<<<1, 256, 0, stream>>>(cursor, nodeBlocks);
    scan3_kernel<<<nodeBlocks, 256, 0, stream>>>(cursor, offs, deg /*reuse as cursor*/, NN);
    fill_kernel<<<edgeBlocks, 256, 0, stream>>>(ei, deg, csrc, ceid);

    // ---- pack mean/log_std weights ----
    pack_ms_kernel<<<16, 256, 0, stream>>>(Wm, Ws, ams, ass, amd, asd, Wms, aSms, aDms);

    dim3 g1(4, (NN + 63) / 64);
    // ---- layer 1 ----
    gemm_kernel<<<g1, 256, 0, stream>>>(x, W1, bufA, NN, 256, 256);
    scores4_kernel<<<waveBlocks, 256, 0, stream>>>(bufA, a1s, a1d, es1, ed1);
    agg_concat_kernel<<<waveBlocks, 256, 0, stream>>>(bufA, es1, ed1, offs, csrc, ceid, b1, bufB, a_w1, etmp);

    // ---- layer 2 ----
    gemm_kernel<<<g1, 256, 0, stream>>>(bufB, W2, bufA, NN, 256, 256);
    scores4_kernel<<<waveBlocks, 256, 0, stream>>>(bufA, a2s, a2d, es2, ed2);
    agg_mean_kernel<<<waveBlocks, 256, 0, stream>>>(bufA, es2, ed2, offs, csrc, ceid, b2, h2, a_w2, etmp);

    // ---- mean / log_std heads ----
    dim3 g2(1, (NN + 63) / 64);
    gemm_kernel<<<g2, 256, 0, stream>>>(h2, Wms, bufB, NN, 64, 64);
    scores_ms_kernel<<<waveBlocks, 256, 0, stream>>>(bufB, aSms, aDms, esms, edms);
    agg_ms_kernel<<<waveBlocks, 256, 0, stream>>>(bufB, esms, edms, offs, csrc, ceid, bm, bs,
                                                  zmean, zlog, a_wm, a_ws_o, etmp);
}